// Round 6
// baseline (213.454 us; speedup 1.0000x reference)
//
#include <hip/hip_runtime.h>

// R12 = radix-4 chain: 4 rounds (3 full barriers + 1 split) instead of 8.
// R11 post-mortem: doubling occupancy changed nothing (62.7 -> 64-66 us,
// VALUBusy ~14%) -> the chain is bound by per-round serial constants
// (sc1 drain + 2-hop IC barrier + IC first-touch), ~6.5 us x 8 rounds.
// Only lever: fewer rounds. One grid-synced MM layer can only double the
// exponent, but BLOCK-LOCAL serial row-MV chains quadruple it per round:
// given S=A^(4^k): row r of S^4 = ((S_r*S)*S)*S  (3 LDS-local MV stages),
// P_{j+c*4^k} = P_j*S^c by the same chain. Rounds: k=0..3 with
// S = A, A^4, A^16, A^64; round k<3: blocks 0..63 square (4 rows each),
// blocks 64..64+4^k-1 extend P; round 3: blocks 0..63 extend P rows
// 64..255. Same validated data scheme as R6/R10: sc1 write-once stores +
// normal cached loads, per-launch-zeroed flags, 2-hop grid barrier,
// split FINAL barrier (pass 1 = t in [192,256) reads P rows 0..63, final
// since barrier 3). us-staging of U moved to just after barrier 1 so its
// IC first-touch hides under the chain.

#define SEQ_T 256
#define DIM 128
#define ORD 256
#define BMROWS 2048

// float offsets into ws (write-once buffers, guard gaps)
#define OFF_U 0                                  // U[t][bm]: 256*2048
#define OFF_P (OFF_U + SEQ_T * BMROWS)           // P[j][o]: 256*256
#define APSTRIDE (ORD * ORD + 2048)
#define OFF_AP (OFF_P + ORD * ORD + 2048)        // AP[k]: A^4, A^16, A^64
#define OFF_FLAGS (OFF_AP + 7 * APSTRIDE + 2048) // 256 flags; gen at +320

#define LD_A(p) \
  __hip_atomic_load((p), __ATOMIC_RELAXED, __HIP_MEMORY_SCOPE_AGENT)
#define ST_A(p, v) \
  __hip_atomic_store((p), (v), __ATOMIC_RELAXED, __HIP_MEMORY_SCOPE_AGENT)

// 2-hop fence-free grid barrier (256 blocks), R6-validated.
__device__ __forceinline__ void gbar(unsigned* flags, unsigned* gen,
                                     unsigned target) {
  asm volatile("s_waitcnt vmcnt(0)" ::: "memory");  // drain this wave's sc1 st
  __syncthreads();  // now ALL waves of the block have drained
  const int tid = threadIdx.x;
  if (blockIdx.x == 0) {
    if (tid == 0) ST_A(&flags[0], target);
    while (LD_A(&flags[tid]) < target) __builtin_amdgcn_s_sleep(1);
    __syncthreads();  // all 256 flags seen
    if (tid == 0) ST_A(gen, target);
  } else {
    if (tid == 0) {
      ST_A(&flags[blockIdx.x], target);
      while (LD_A(gen) < target) __builtin_amdgcn_s_sleep(1);
    }
  }
  __syncthreads();
}

__global__ __launch_bounds__(256) void lrmu_all(
    const float* __restrict__ x, const float* __restrict__ K,
    const float* __restrict__ A, const float* __restrict__ Bm,
    float* __restrict__ out, float* __restrict__ ws) {
  __shared__ __align__(16) float Slds[8192];  // 32 KB: U xs / out redo
  __shared__ __align__(16) float us[2048];    // 8 KB: out U rows (early)
  __shared__ __align__(16) float xb0[1024];   // 4 KB: chain x (i-major [i][4])
  __shared__ __align__(16) float xb1[1024];   // 4 KB: chain x double buffer
  float* U = ws + OFF_U;
  float* P = ws + OFF_P;
  unsigned* flags = (unsigned*)(ws + OFF_FLAGS);
  unsigned* gen = flags + 320;
  const int blk = blockIdx.x, tid = threadIdx.x;

  // ---------- U phase: U[t][bm] = sum_d x[b][t][d] * K[d][m] ----------
  {
    int b = blk >> 4, tc = blk & 15;
    float* xs = Slds;
    for (int idx = tid; idx < 16 * DIM; idx += 256)
      xs[idx] = x[(b * SEQ_T + tc * 16) * DIM + idx];
    __syncthreads();
    int m = tid & 127, th = tid >> 7;
    float acc[8] = {};
#pragma unroll 8
    for (int d = 0; d < DIM; ++d) {
      float kv = K[d * DIM + m];  // coalesced, L2-resident
#pragma unroll
      for (int r = 0; r < 8; ++r)
        acc[r] = fmaf(xs[(th * 8 + r) * DIM + d], kv, acc[r]);
    }
#pragma unroll
    for (int r = 0; r < 8; ++r)  // sc1: read cross-XCD at out phase
      ST_A(&U[(tc * 16 + th * 8 + r) * BMROWS + b * DIM + m], acc[r]);
    if (blk == 0) ST_A(&P[tid], Bm[tid]);  // P[0][:] = b
    __syncthreads();  // before Slds reuse
  }

  // ---------- chain: 4 radix-4 rounds of block-local serial MV chains ----
  for (int k = 0; k < 4; ++k) {
    const int stride = 1 << (2 * k);  // 4^k
    const float* Smat = (k == 0) ? A : (ws + OFF_AP + (k - 1) * APSTRIDE);
    float* Snew = ws + OFF_AP + k * APSTRIDE;  // k=3 writes none
    const bool sq = (k < 3) && (blk < 64);
    const bool pr = (k < 3) ? (blk >= 64 && blk < 64 + stride) : (blk < 64);
    const int j = (k < 3) ? (blk - 64) : blk;

    if (sq || pr) {
      float* xc = xb0;
      float* xn = xb1;
      if (sq) {  // 4 chains: rows 4*blk+s of S
        float4 v;
        v.x = Smat[(4 * blk + 0) * ORD + tid];
        v.y = Smat[(4 * blk + 1) * ORD + tid];
        v.z = Smat[(4 * blk + 2) * ORD + tid];
        v.w = Smat[(4 * blk + 3) * ORD + tid];
        *(float4*)&xc[4 * tid] = v;
      } else {  // 1 chain: P row j (write-once, final since last barrier)
        float s0 = (k == 0) ? Bm[tid] : P[j * ORD + tid];
        *(float4*)&xc[4 * tid] = make_float4(s0, 0.f, 0.f, 0.f);
      }
      __syncthreads();
#pragma unroll
      for (int st = 0; st < 3; ++st) {
        float a0 = 0.f, a1 = 0.f, a2 = 0.f, a3 = 0.f;
        const float* Sc = Smat + tid;  // thread owns column tid
#pragma unroll 4
        for (int i = 0; i < 256; ++i) {
          float4 xv = *(const float4*)&xc[4 * i];  // b128 broadcast
          float sv = Sc[i * ORD];                  // coalesced global
          a0 = fmaf(xv.x, sv, a0);
          a1 = fmaf(xv.y, sv, a1);
          a2 = fmaf(xv.z, sv, a2);
          a3 = fmaf(xv.w, sv, a3);
        }
        if (pr)  // chain 0 output row j + (st+1)*4^k
          ST_A(&P[(j + (st + 1) * stride) * ORD + tid], a0);
        if (st < 2) {
          *(float4*)&xn[4 * tid] = make_float4(a0, a1, a2, a3);
          __syncthreads();
          float* t2 = xc; xc = xn; xn = t2;
        } else if (sq) {  // S^4 rows out
          ST_A(&Snew[(4 * blk + 0) * ORD + tid], a0);
          ST_A(&Snew[(4 * blk + 1) * ORD + tid], a1);
          ST_A(&Snew[(4 * blk + 2) * ORD + tid], a2);
          ST_A(&Snew[(4 * blk + 3) * ORD + tid], a3);
        }
      }
    }

    if (k < 3) {
      gbar(flags, gen, (unsigned)(k + 1));
      if (k == 0) {  // U globally visible now: stage us early (IC latency
                     // hides under rounds 1-3 instead of the out phase)
        int bm0 = blk * 8;
        for (int idx = tid; idx < SEQ_T * 8; idx += 256) {
          int t = idx >> 3, r = idx & 7;
          us[idx] = U[t * BMROWS + bm0 + r];
        }
      }
    }
  }

  // ---------- round-3 ARRIVE (split gbar, target 4) ----------
  asm volatile("s_waitcnt vmcnt(0)" ::: "memory");  // drain P[64..255] sc1 st
  __syncthreads();
  if (tid == 0) ST_A(&flags[blk], 4u);

  // ---------- out: out[bm][o] = sum_t U[t][bm] * P[255-t][o] ----------
  // pass 1: t in [192,256) reads P rows 0..63 (final since barrier 3);
  // pass 2: t in [0,192) reads rows 64..255 after the barrier completes.
  {
    float* redo = Slds;  // [4][8][256] wave partials
    int bm0 = blk * 8;
    __syncthreads();  // us fully staged (gbar syncs passed, keep explicit)
    const int lane = tid & 63, qo = tid >> 6;
    int c4o = lane * 4;
    float ao[8][4] = {};
    // pass 1: wave qo covers t = 192 + [16qo, 16qo+16)
#pragma unroll 4
    for (int tt = 0; tt < 16; ++tt) {
      int t = 192 + qo * 16 + tt;
      float4 pv = *(const float4*)&P[(SEQ_T - 1 - t) * ORD + c4o];
      float4 u0 = *(const float4*)&us[t * 8];
      float4 u1 = *(const float4*)&us[t * 8 + 4];
      float uv[8] = {u0.x, u0.y, u0.z, u0.w, u1.x, u1.y, u1.z, u1.w};
      float pw[4] = {pv.x, pv.y, pv.z, pv.w};
#pragma unroll
      for (int r = 0; r < 8; ++r)
#pragma unroll
        for (int w = 0; w < 4; ++w) ao[r][w] = fmaf(uv[r], pw[w], ao[r][w]);
    }
    // ---------- complete final barrier (latency hidden under pass 1) ----
    if (blk == 0) {
      while (LD_A(&flags[tid]) < 4u) __builtin_amdgcn_s_sleep(1);
      __syncthreads();  // all 256 flags seen
      if (tid == 0) ST_A(gen, 4u);
    } else {
      if (tid == 0)
        while (LD_A(gen) < 4u) __builtin_amdgcn_s_sleep(1);
    }
    __syncthreads();
    // pass 2: wave qo covers t = [48qo, 48qo+48); P rows 64..255 now final
#pragma unroll 4
    for (int tt = 0; tt < 48; ++tt) {
      int t = qo * 48 + tt;
      float4 pv = *(const float4*)&P[(SEQ_T - 1 - t) * ORD + c4o];
      float4 u0 = *(const float4*)&us[t * 8];
      float4 u1 = *(const float4*)&us[t * 8 + 4];
      float uv[8] = {u0.x, u0.y, u0.z, u0.w, u1.x, u1.y, u1.z, u1.w};
      float pw[4] = {pv.x, pv.y, pv.z, pv.w};
#pragma unroll
      for (int r = 0; r < 8; ++r)
#pragma unroll
        for (int w = 0; w < 4; ++w) ao[r][w] = fmaf(uv[r], pw[w], ao[r][w]);
    }
#pragma unroll
    for (int r = 0; r < 8; ++r)
      *(float4*)&redo[qo * 2048 + r * 256 + c4o] =
          make_float4(ao[r][0], ao[r][1], ao[r][2], ao[r][3]);
    __syncthreads();
#pragma unroll
    for (int j2 = 0; j2 < 8; ++j2) {
      int o = tid + 256 * j2;  // o = r*256 + c
      float s = redo[o] + redo[2048 + o] + redo[4096 + o] + redo[6144 + o];
      out[bm0 * ORD + o] = s;  // kernel-end release flushes
    }
  }
}

extern "C" void kernel_launch(void* const* d_in, const int* in_sizes, int n_in,
                              void* d_out, int out_size, void* d_ws,
                              size_t ws_size, hipStream_t stream) {
  const float* x = (const float*)d_in[0];   // (16,256,128)
  const float* K = (const float*)d_in[1];   // (128,128)
  const float* A = (const float*)d_in[2];   // (256,256)
  const float* Bm = (const float*)d_in[3];  // (256,)
  float* out = (float*)d_out;               // (16, 32768)
  float* ws = (float*)d_ws;

  // zero barrier flags + gen (ws re-poisoned 0xAA before every timed call)
  hipMemsetAsync(ws + OFF_FLAGS, 0, 2048, stream);
  lrmu_all<<<256, 256, 0, stream>>>(x, K, A, Bm, out, ws);
}

// Round 7
// 121.783 us; speedup vs baseline: 1.7527x; 1.7527x over previous
//
#include <hip/hip_runtime.h>

// R13 = R10 (validated 118.1 us) with round 7 ABSORBED into the out phase.
// R12 post-mortem: serial per-block MV chains over global are latency-bound
// (VALUBusy 5.6%, 158 us) — only barrier-separated LDS-staged layers work.
// R11: occupancy doesn't help. R10: ~1-2 us/barrier hideable. So the chain
// is 8 rounds x ~6.5 us of near-irreducible constants; the one algebraic cut:
//   sum_{t<128} U[t] P[255-t] = (sum_{t<128} U[t] P[127-t]) * A^128
// so round 7 (P[128+j] = P[j]*A^128) is replaced by a per-block V2*A^128
// MV in the out phase (LDS-banded, throughput-style). Chain = rounds 0..6
// (6 full barriers + 1 split/hidden). Same validated data scheme: sc1
// write-once stores + normal cached loads, 2-hop fence-free barrier.
// Out: pass-1 (t in [192,256), P rows 0..63 final since barrier 6) hides
// barrier-7 completion; then pass-2 (t in [128,192)), V2 accumulation
// (t in [0,128)), wave-reduce of V2, and the banded V2*A^128 MV whose
// wave-partials join the existing final reduction.

#define SEQ_T 256
#define DIM 128
#define ORD 256
#define BMROWS 2048

// float offsets into ws (write-once buffers, guard gaps)
#define OFF_U 0                                  // U[t][bm]: 256*2048
#define OFF_P (OFF_U + SEQ_T * BMROWS)           // P[j][o]: rows 0..127 used
#define APSTRIDE (ORD * ORD + 2048)
#define OFF_AP (OFF_P + ORD * ORD + 2048)        // AP[k]=A^(2^(k+1)), k=0..6
#define OFF_FLAGS (OFF_AP + 7 * APSTRIDE + 2048) // 256 flags; gen at +320

#define LD_A(p) \
  __hip_atomic_load((p), __ATOMIC_RELAXED, __HIP_MEMORY_SCOPE_AGENT)
#define ST_A(p, v) \
  __hip_atomic_store((p), (v), __ATOMIC_RELAXED, __HIP_MEMORY_SCOPE_AGENT)

// 2-hop fence-free grid barrier (256 blocks), R6-validated.
__device__ __forceinline__ void gbar(unsigned* flags, unsigned* gen,
                                     unsigned target) {
  asm volatile("s_waitcnt vmcnt(0)" ::: "memory");  // drain this wave's sc1 st
  __syncthreads();  // now ALL waves of the block have drained
  const int tid = threadIdx.x;
  if (blockIdx.x == 0) {
    if (tid == 0) ST_A(&flags[0], target);
    while (LD_A(&flags[tid]) < target) __builtin_amdgcn_s_sleep(1);
    __syncthreads();  // all 256 flags seen
    if (tid == 0) ST_A(gen, target);
  } else {
    if (tid == 0) {
      ST_A(&flags[blockIdx.x], target);
      while (LD_A(gen) < target) __builtin_amdgcn_s_sleep(1);
    }
  }
  __syncthreads();
}

__global__ __launch_bounds__(256) void lrmu_all(
    const float* __restrict__ x, const float* __restrict__ K,
    const float* __restrict__ A, const float* __restrict__ Bm,
    float* __restrict__ out, float* __restrict__ ws) {
  __shared__ __align__(16) float Slds[ORD * 64];  // 64 KB: S slice / redo+band
  __shared__ __align__(16) float lsb[2048];       // 8 KB: chain left rows / us
  __shared__ __align__(16) float redb[4 * 320];   // 5 KB: chain wave partials
  __shared__ __align__(16) float v2b[2048];       // 8 KB: V2[8][256]
  float* U = ws + OFF_U;
  float* P = ws + OFF_P;
  unsigned* flags = (unsigned*)(ws + OFF_FLAGS);
  unsigned* gen = flags + 320;
  const int blk = blockIdx.x, tid = threadIdx.x;

  // ---------- U phase: U[t][bm] = sum_d x[b][t][d] * K[d][m] ----------
  {
    int b = blk >> 4, tc = blk & 15;
    float* xs = Slds;
    for (int idx = tid; idx < 16 * DIM; idx += 256)
      xs[idx] = x[(b * SEQ_T + tc * 16) * DIM + idx];
    __syncthreads();
    int m = tid & 127, th = tid >> 7;
    float acc[8] = {};
#pragma unroll 8
    for (int d = 0; d < DIM; ++d) {
      float kv = K[d * DIM + m];  // coalesced, L2-resident
#pragma unroll
      for (int r = 0; r < 8; ++r)
        acc[r] = fmaf(xs[(th * 8 + r) * DIM + d], kv, acc[r]);
    }
#pragma unroll
    for (int r = 0; r < 8; ++r)  // sc1: read cross-XCD at out phase
      ST_A(&U[(tc * 16 + th * 8 + r) * BMROWS + b * DIM + m], acc[r]);
    if (blk == 0) ST_A(&P[tid], Bm[tid]);  // P[0][:] = b
    __syncthreads();  // before Slds reuse in chain
  }

  // ---------- chain: rounds k=0..6; square to A^128, extend P to row 127 --
  const int rg = blk >> 2, cg = blk & 3;
  const int lane = tid & 63, q = tid >> 6;
  const int ir = lane >> 4, c4 = (lane & 15) * 4;
  for (int k = 0; k < 7; ++k) {
    const float* S = (k == 0) ? A : (ws + OFF_AP + (k - 1) * APSTRIDE);
    float* Snew = ws + OFF_AP + k * APSTRIDE;  // AP[6] = A^128
    const int half = 1 << k;
    const int ndb = (rg < half) ? 1 : 0;  // P-extension rows this block
    const int nrows = 4 + ndb;

    // stage left rows into lsb[5][256]; zero-pad unused
#pragma unroll
    for (int s = 0; s < 5; ++s) {
      float v = 0.f;
      if (s < 4) {
        v = S[(4 * rg + s) * ORD + tid];
      } else if (ndb) {
        v = (k == 0) ? Bm[tid] : P[rg * ORD + tid];  // write-once P rows
      }
      lsb[s * ORD + tid] = v;
    }
    // stage right slice S[:, 64cg..+64) into Slds[256][64] via float4
#pragma unroll
    for (int j = 0; j < 16; ++j) {
      int f = tid + 256 * j;
      int i = f >> 4, cc = (f & 15) * 4;
      *(float4*)&Slds[i * 64 + cc] =
          *(const float4*)&S[i * ORD + cg * 64 + cc];
    }
    __syncthreads();

    // wave q covers K-chunk [64q,64q+64); lane = (ir K-subsplit, c4 cols)
    float acc[5][4] = {};
#pragma unroll 4
    for (int ii = 0; ii < 16; ++ii) {
      int i = q * 64 + 4 * ii + ir;
      float4 sv = *(const float4*)&Slds[i * 64 + c4];  // b128 LDS
#pragma unroll
      for (int s = 0; s < 5; ++s) {
        float lv = lsb[s * ORD + i];  // broadcast
        acc[s][0] = fmaf(lv, sv.x, acc[s][0]);
        acc[s][1] = fmaf(lv, sv.y, acc[s][1]);
        acc[s][2] = fmaf(lv, sv.z, acc[s][2]);
        acc[s][3] = fmaf(lv, sv.w, acc[s][3]);
      }
    }
#pragma unroll
    for (int s = 0; s < 5; ++s)
#pragma unroll
      for (int w = 0; w < 4; ++w) {
        acc[s][w] += __shfl_xor(acc[s][w], 16);
        acc[s][w] += __shfl_xor(acc[s][w], 32);
      }
    if (ir == 0) {
#pragma unroll
      for (int s = 0; s < 5; ++s)
        *(float4*)&redb[q * 320 + s * 64 + c4] =
            make_float4(acc[s][0], acc[s][1], acc[s][2], acc[s][3]);
    }
    __syncthreads();
    for (int o = tid; o < 320; o += 256) {
      int s = o >> 6, c = o & 63;
      if (s < nrows) {
        float sum = redb[o] + redb[320 + o] + redb[640 + o] + redb[960 + o];
        if (s < 4) {
          ST_A(&Snew[(4 * rg + s) * ORD + cg * 64 + c], sum);
        } else {
          ST_A(&P[(half + rg) * ORD + cg * 64 + c], sum);
        }
      }
    }
    if (k < 6) gbar(flags, gen, (unsigned)(k + 1));
  }

  // ---------- round-6 ARRIVE (split gbar, target 7) ----------
  asm volatile("s_waitcnt vmcnt(0)" ::: "memory");  // drain P[64..127]+A^128
  __syncthreads();  // all waves drained; lsb/redb reads done
  if (tid == 0) ST_A(&flags[blk], 7u);

  // ---------- out: out[bm] = sum_{t>=128} U[t] P[255-t]  +  V2 * A^128 ----
  // pass 1: t in [192,256) reads P rows 0..63 (final since barrier 6) and
  // hides barrier-7 completion; pass 2: t in [128,192) reads rows 64..127;
  // V2 = sum_{t<128} U[t] P[127-t]; then banded MV by A^128 (= AP[6]).
  {
    float* us = lsb;                  // [256][8]
    float* redo = Slds;               // [4][8][256] wave partials (32 KB)
    float* band = Slds + 8192;        // A^128 rows band (32 KB)
    const float* A128 = ws + OFF_AP + 6 * APSTRIDE;
    int bm0 = blk * 8;
    for (int idx = tid; idx < SEQ_T * 8; idx += 256) {
      int t = idx >> 3, r = idx & 7;
      us[idx] = U[t * BMROWS + bm0 + r];  // normal load: first touch of U
    }
    __syncthreads();
    int c4o = lane * 4, qo = q;
    float ao[8][4] = {};
    // pass 1: wave qo covers t = 192 + [16qo, 16qo+16)
#pragma unroll 4
    for (int tt = 0; tt < 16; ++tt) {
      int t = 192 + qo * 16 + tt;
      float4 pv = *(const float4*)&P[(SEQ_T - 1 - t) * ORD + c4o];  // L2-hot
      float4 u0 = *(const float4*)&us[t * 8];  // LDS broadcast
      float4 u1 = *(const float4*)&us[t * 8 + 4];
      float uv[8] = {u0.x, u0.y, u0.z, u0.w, u1.x, u1.y, u1.z, u1.w};
      float pw[4] = {pv.x, pv.y, pv.z, pv.w};
#pragma unroll
      for (int r = 0; r < 8; ++r)
#pragma unroll
        for (int w = 0; w < 4; ++w)
          ao[r][w] = fmaf(uv[r], pw[w], ao[r][w]);
    }
    // ---------- complete final barrier (latency hidden under pass 1) ----
    if (blk == 0) {
      while (LD_A(&flags[tid]) < 7u) __builtin_amdgcn_s_sleep(1);
      __syncthreads();  // all 256 flags seen
      if (tid == 0) ST_A(gen, 7u);
    } else {
      if (tid == 0)
        while (LD_A(gen) < 7u) __builtin_amdgcn_s_sleep(1);
    }
    __syncthreads();
    // pass 2: t = 128 + [16qo,16qo+16); P rows 64..127 now final
#pragma unroll 4
    for (int tt = 0; tt < 16; ++tt) {
      int t = 128 + qo * 16 + tt;
      float4 pv = *(const float4*)&P[(SEQ_T - 1 - t) * ORD + c4o];
      float4 u0 = *(const float4*)&us[t * 8];
      float4 u1 = *(const float4*)&us[t * 8 + 4];
      float uv[8] = {u0.x, u0.y, u0.z, u0.w, u1.x, u1.y, u1.z, u1.w};
      float pw[4] = {pv.x, pv.y, pv.z, pv.w};
#pragma unroll
      for (int r = 0; r < 8; ++r)
#pragma unroll
        for (int w = 0; w < 4; ++w)
          ao[r][w] = fmaf(uv[r], pw[w], ao[r][w]);
    }
    // V2 partials: wave qo covers t = [32qo, 32qo+32)
    float vo[8][4] = {};
#pragma unroll 4
    for (int tt = 0; tt < 32; ++tt) {
      int t = qo * 32 + tt;
      float4 pv = *(const float4*)&P[(127 - t) * ORD + c4o];
      float4 u0 = *(const float4*)&us[t * 8];
      float4 u1 = *(const float4*)&us[t * 8 + 4];
      float uv[8] = {u0.x, u0.y, u0.z, u0.w, u1.x, u1.y, u1.z, u1.w};
      float pw[4] = {pv.x, pv.y, pv.z, pv.w};
#pragma unroll
      for (int r = 0; r < 8; ++r)
#pragma unroll
        for (int w = 0; w < 4; ++w)
          vo[r][w] = fmaf(uv[r], pw[w], vo[r][w]);
    }
    // reduce V2 over waves into v2b[8][256]
#pragma unroll
    for (int r = 0; r < 8; ++r)
      *(float4*)&redo[qo * 2048 + r * 256 + c4o] =
          make_float4(vo[r][0], vo[r][1], vo[r][2], vo[r][3]);
    __syncthreads();
#pragma unroll
    for (int j = 0; j < 8; ++j) {
      int o = tid + 256 * j;
      v2b[o] = redo[o] + redo[2048 + o] + redo[4096 + o] + redo[6144 + o];
    }
    __syncthreads();
    // banded MV: ao += V2 * A^128, 8 bands of 32 rows; wave qo takes an
    // 8-row slice per band -> wave-partials join the final reduction.
    for (int b = 0; b < 8; ++b) {
#pragma unroll
      for (int j = 0; j < 8; ++j) {  // stage rows [32b, 32b+32) (8 KB/thr gr)
        int f = tid + 256 * j;
        int il = f >> 6, cc = (f & 63) * 4;
        *(float4*)&band[il * 256 + cc] =
            *(const float4*)&A128[(32 * b + il) * ORD + cc];
      }
      __syncthreads();
#pragma unroll
      for (int ii = 0; ii < 8; ++ii) {
        int il = 8 * qo + ii;  // local row in band
        float4 av = *(const float4*)&band[il * 256 + c4o];  // b128, even banks
        float aw[4] = {av.x, av.y, av.z, av.w};
#pragma unroll
        for (int r = 0; r < 8; ++r) {
          float lv = v2b[r * 256 + 32 * b + il];  // broadcast
#pragma unroll
          for (int w = 0; w < 4; ++w)
            ao[r][w] = fmaf(lv, aw[w], ao[r][w]);
        }
      }
      __syncthreads();
    }
    // final reduce over waves and store
#pragma unroll
    for (int r = 0; r < 8; ++r)
      *(float4*)&redo[qo * 2048 + r * 256 + c4o] =
          make_float4(ao[r][0], ao[r][1], ao[r][2], ao[r][3]);
    __syncthreads();
#pragma unroll
    for (int j = 0; j < 8; ++j) {
      int o = tid + 256 * j;  // o = r*256 + c
      float s = redo[o] + redo[2048 + o] + redo[4096 + o] + redo[6144 + o];
      out[bm0 * ORD + o] = s;  // kernel-end release flushes
    }
  }
}

extern "C" void kernel_launch(void* const* d_in, const int* in_sizes, int n_in,
                              void* d_out, int out_size, void* d_ws,
                              size_t ws_size, hipStream_t stream) {
  const float* x = (const float*)d_in[0];   // (16,256,128)
  const float* K = (const float*)d_in[1];   // (128,128)
  const float* A = (const float*)d_in[2];   // (256,256)
  const float* Bm = (const float*)d_in[3];  // (256,)
  float* out = (float*)d_out;               // (16, 32768)
  float* ws = (float*)d_ws;

  // zero barrier flags + gen (ws re-poisoned 0xAA before every timed call)
  hipMemsetAsync(ws + OFF_FLAGS, 0, 2048, stream);
  lrmu_all<<<256, 256, 0, stream>>>(x, K, A, Bm, out, ws);
}

// Round 8
// 120.897 us; speedup vs baseline: 1.7656x; 1.0073x over previous
//
#include <hip/hip_runtime.h>

// R14 = R10 (validated best, 118.08 us) + two latency-hiding reorderings.
// R13 post-mortem: absorbing round 7 into the out phase LOST ~2 us (banded
// A^128 restaging + V2 reduce + VGPR 132 cost more than the saved barrier).
// Reverted to R10's 8-round chain. R14 hides two serial staging segments:
//  (1) us-staging of U (IC first-touch, ~1.5 us) moves from the out-phase
//      critical path to right after barrier 1 (U globally visible there);
//      ~6 chain rounds hide it. Separate 8 KB usb buffer.
//  (2) round-0's right-slice staging of A (64 KB/block) is prefetched into
//      Slds during the U phase (xs moves to its own buffer), so round 0
//      starts computing immediately.
// Everything else is R10 verbatim: sc1 write-once stores + normal cached
// loads, 8 distinct A-power buffers, 2-hop fence-free grid barrier, split
// FINAL barrier (arrive after round-7 drain; t>=128 out-half; complete
// barrier; t<128 half).

#define SEQ_T 256
#define DIM 128
#define ORD 256
#define BMROWS 2048

// float offsets into ws (write-once buffers, guard gaps)
#define OFF_U 0                                  // U[t][bm]: 256*2048
#define OFF_P (OFF_U + SEQ_T * BMROWS)           // P[j][o]: 256*256
#define APSTRIDE (ORD * ORD + 2048)
#define OFF_AP (OFF_P + ORD * ORD + 2048)        // AP[j]=A^(2^(j+1))
#define OFF_FLAGS (OFF_AP + 7 * APSTRIDE + 2048) // 256 flags; gen at +320

#define LD_A(p) \
  __hip_atomic_load((p), __ATOMIC_RELAXED, __HIP_MEMORY_SCOPE_AGENT)
#define ST_A(p, v) \
  __hip_atomic_store((p), (v), __ATOMIC_RELAXED, __HIP_MEMORY_SCOPE_AGENT)

// 2-hop fence-free grid barrier (256 blocks). No __threadfence anywhere;
// correctness comes from sc1 write-once buffers + vmcnt drain before arrival.
__device__ __forceinline__ void gbar(unsigned* flags, unsigned* gen,
                                     unsigned target) {
  asm volatile("s_waitcnt vmcnt(0)" ::: "memory");  // drain this wave's sc1 st
  __syncthreads();  // now ALL waves of the block have drained
  const int tid = threadIdx.x;
  if (blockIdx.x == 0) {
    if (tid == 0) ST_A(&flags[0], target);
    while (LD_A(&flags[tid]) < target) __builtin_amdgcn_s_sleep(1);
    __syncthreads();  // all 256 flags seen
    if (tid == 0) ST_A(gen, target);
  } else {
    if (tid == 0) {
      ST_A(&flags[blockIdx.x], target);
      while (LD_A(gen) < target) __builtin_amdgcn_s_sleep(1);
    }
  }
  __syncthreads();
}

__global__ __launch_bounds__(256) void lrmu_all(
    const float* __restrict__ x, const float* __restrict__ K,
    const float* __restrict__ A, const float* __restrict__ Bm,
    float* __restrict__ out, float* __restrict__ ws) {
  __shared__ __align__(16) float Slds[ORD * 64];  // 64 KB: S col-slice / redo
  __shared__ __align__(16) float xsb[2048];       // 8 KB: U-phase x staging
  __shared__ __align__(16) float lsb[2048];       // 8 KB: chain left rows
  __shared__ __align__(16) float redb[4 * 320];   // 5 KB: chain wave partials
  __shared__ __align__(16) float usb[2048];       // 8 KB: out U rows (early)
  float* U = ws + OFF_U;
  float* P = ws + OFF_P;
  unsigned* flags = (unsigned*)(ws + OFF_FLAGS);
  unsigned* gen = flags + 320;
  const int blk = blockIdx.x, tid = threadIdx.x;
  const int rg = blk >> 2, cg = blk & 3;
  const int lane = tid & 63, q = tid >> 6;
  const int ir = lane >> 4, c4 = (lane & 15) * 4;

  // ---------- U phase: U[t][bm] = sum_d x[b][t][d] * K[d][m] ----------
  // Concurrently prefetch round-0's right slice A[:, 64cg..+64) into Slds.
  {
    int b = blk >> 4, tc = blk & 15;
    for (int idx = tid; idx < 16 * DIM; idx += 256)
      xsb[idx] = x[(b * SEQ_T + tc * 16) * DIM + idx];
#pragma unroll
    for (int j = 0; j < 16; ++j) {  // A slice prefetch (L2-resident input)
      int f = tid + 256 * j;
      int i = f >> 4, cc = (f & 15) * 4;
      *(float4*)&Slds[i * 64 + cc] =
          *(const float4*)&A[i * ORD + cg * 64 + cc];
    }
    __syncthreads();
    int m = tid & 127, th = tid >> 7;
    float acc[8] = {};
#pragma unroll 8
    for (int d = 0; d < DIM; ++d) {
      float kv = K[d * DIM + m];  // coalesced, L2-resident
#pragma unroll
      for (int r = 0; r < 8; ++r)
        acc[r] = fmaf(xsb[(th * 8 + r) * DIM + d], kv, acc[r]);
    }
#pragma unroll
    for (int r = 0; r < 8; ++r)  // sc1: read cross-XCD at out phase
      ST_A(&U[(tc * 16 + th * 8 + r) * BMROWS + b * DIM + m], acc[r]);
    if (blk == 0) ST_A(&P[tid], Bm[tid]);  // P[0][:] = b
  }

  // ---------- chain: step k reads S=A^(2^k), writes S^2 and P doubling ----
  for (int k = 0; k < 8; ++k) {
    const float* S = (k == 0) ? A : (ws + OFF_AP + (k - 1) * APSTRIDE);
    float* Snew = ws + OFF_AP + ((k < 7) ? k : 6) * APSTRIDE;  // unused k=7
    const int half = 1 << k;
    const int nsq = (k < 7) ? 4 : 0;
    const int ndb = (k == 7) ? 2 : (rg < half ? 1 : 0);
    const int nrows = nsq + ndb;

    // stage left rows into lsb[5][256]; zero-pad unused
#pragma unroll
    for (int s = 0; s < 5; ++s) {
      float v = 0.f;
      if (s < nsq) {
        v = S[(4 * rg + s) * ORD + tid];
      } else if (s - nsq < ndb) {
        int d = rg + 64 * (s - nsq);
        v = (k == 0) ? Bm[tid] : P[d * ORD + tid];  // write-once P rows
      }
      lsb[s * ORD + tid] = v;
    }
    if (k != 0) {  // k=0 slice was prefetched during the U phase
      // stage right slice S[:, 64cg..+64) into Slds[256][64] via float4
#pragma unroll
      for (int j = 0; j < 16; ++j) {
        int f = tid + 256 * j;
        int i = f >> 4, cc = (f & 15) * 4;
        *(float4*)&Slds[i * 64 + cc] =
            *(const float4*)&S[i * ORD + cg * 64 + cc];
      }
    }
    __syncthreads();

    // wave q covers K-chunk [64q,64q+64); lane = (ir K-subsplit, c4 cols)
    float acc[5][4] = {};
#pragma unroll 4
    for (int ii = 0; ii < 16; ++ii) {
      int i = q * 64 + 4 * ii + ir;
      float4 sv = *(const float4*)&Slds[i * 64 + c4];  // b128 LDS
#pragma unroll
      for (int s = 0; s < 5; ++s) {
        float lv = lsb[s * ORD + i];  // broadcast
        acc[s][0] = fmaf(lv, sv.x, acc[s][0]);
        acc[s][1] = fmaf(lv, sv.y, acc[s][1]);
        acc[s][2] = fmaf(lv, sv.z, acc[s][2]);
        acc[s][3] = fmaf(lv, sv.w, acc[s][3]);
      }
    }
#pragma unroll
    for (int s = 0; s < 5; ++s)
#pragma unroll
      for (int w = 0; w < 4; ++w) {
        acc[s][w] += __shfl_xor(acc[s][w], 16);
        acc[s][w] += __shfl_xor(acc[s][w], 32);
      }
    if (ir == 0) {
#pragma unroll
      for (int s = 0; s < 5; ++s)
        *(float4*)&redb[q * 320 + s * 64 + c4] =
            make_float4(acc[s][0], acc[s][1], acc[s][2], acc[s][3]);
    }
    __syncthreads();
    for (int o = tid; o < 320; o += 256) {
      int s = o >> 6, c = o & 63;
      if (s < nrows) {
        float sum = redb[o] + redb[320 + o] + redb[640 + o] + redb[960 + o];
        if (s < nsq) {
          ST_A(&Snew[(4 * rg + s) * ORD + cg * 64 + c], sum);
        } else {
          int d = rg + 64 * (s - nsq);
          ST_A(&P[(half + d) * ORD + cg * 64 + c], sum);
        }
      }
    }
    if (k < 7) {
      gbar(flags, gen, (unsigned)(k + 1));
      if (k == 0) {
        // U globally visible now (barrier-1 drain covered all U stores):
        // stage out-phase U rows early; rounds 1-7 hide the IC first-touch.
        int bm0 = blk * 8;
        for (int idx = tid; idx < SEQ_T * 8; idx += 256) {
          int t = idx >> 3, r = idx & 7;
          usb[idx] = U[t * BMROWS + bm0 + r];
        }
      }
    }
  }

  // ---------- round-7 ARRIVE (split gbar, target 8) ----------
  asm volatile("s_waitcnt vmcnt(0)" ::: "memory");  // drain P[128..255] sc1 st
  __syncthreads();  // all waves drained; lsb/redb/Slds reads done
  if (tid == 0) ST_A(&flags[blk], 8u);

  // ---------- out: out[bm][o] = sum_t U[t][bm] * P[255-t][o] ----------
  // pass 1 (t in [128,256)) reads P rows 0..127 (final since barrier 7);
  // pass 2 (t in [0,128)) reads rows 128..255 after the barrier completes.
  {
    float* redo = Slds;  // [4][8][256] wave partials
    int bm0 = blk * 8;
    int c4o = lane * 4, qo = q;
    float ao[8][4] = {};
    // pass 1: wave qo covers t = 128 + [32qo, 32qo+32)
#pragma unroll 4
    for (int tt = 0; tt < 32; ++tt) {
      int t = 128 + qo * 32 + tt;
      float4 pv = *(const float4*)&P[(SEQ_T - 1 - t) * ORD + c4o];  // L2-hot
      float4 u0 = *(const float4*)&usb[t * 8];  // LDS broadcast (staged early)
      float4 u1 = *(const float4*)&usb[t * 8 + 4];
      float uv[8] = {u0.x, u0.y, u0.z, u0.w, u1.x, u1.y, u1.z, u1.w};
      float pw[4] = {pv.x, pv.y, pv.z, pv.w};
#pragma unroll
      for (int r = 0; r < 8; ++r)
#pragma unroll
        for (int w = 0; w < 4; ++w)
          ao[r][w] = fmaf(uv[r], pw[w], ao[r][w]);
    }
    // ---------- complete final barrier (latency hidden under pass 1) ----
    if (blk == 0) {
      while (LD_A(&flags[tid]) < 8u) __builtin_amdgcn_s_sleep(1);
      __syncthreads();  // all 256 flags seen
      if (tid == 0) ST_A(gen, 8u);
    } else {
      if (tid == 0)
        while (LD_A(gen) < 8u) __builtin_amdgcn_s_sleep(1);
    }
    __syncthreads();
    // pass 2: wave qo covers t = [32qo, 32qo+32); P rows 128..255 now final
#pragma unroll 4
    for (int tt = 0; tt < 32; ++tt) {
      int t = qo * 32 + tt;
      float4 pv = *(const float4*)&P[(SEQ_T - 1 - t) * ORD + c4o];
      float4 u0 = *(const float4*)&usb[t * 8];
      float4 u1 = *(const float4*)&usb[t * 8 + 4];
      float uv[8] = {u0.x, u0.y, u0.z, u0.w, u1.x, u1.y, u1.z, u1.w};
      float pw[4] = {pv.x, pv.y, pv.z, pv.w};
#pragma unroll
      for (int r = 0; r < 8; ++r)
#pragma unroll
        for (int w = 0; w < 4; ++w)
          ao[r][w] = fmaf(uv[r], pw[w], ao[r][w]);
    }
#pragma unroll
    for (int r = 0; r < 8; ++r)
      *(float4*)&redo[qo * 2048 + r * 256 + c4o] =
          make_float4(ao[r][0], ao[r][1], ao[r][2], ao[r][3]);
    __syncthreads();
#pragma unroll
    for (int j = 0; j < 8; ++j) {
      int o = tid + 256 * j;  // o = r*256 + c
      float s = redo[o] + redo[2048 + o] + redo[4096 + o] + redo[6144 + o];
      out[bm0 * ORD + o] = s;  // kernel-end release flushes
    }
  }
}

extern "C" void kernel_launch(void* const* d_in, const int* in_sizes, int n_in,
                              void* d_out, int out_size, void* d_ws,
                              size_t ws_size, hipStream_t stream) {
  const float* x = (const float*)d_in[0];   // (16,256,128)
  const float* K = (const float*)d_in[1];   // (128,128)
  const float* A = (const float*)d_in[2];   // (256,256)
  const float* Bm = (const float*)d_in[3];  // (256,)
  float* out = (float*)d_out;               // (16, 32768)
  float* ws = (float*)d_ws;

  // zero barrier flags + gen (ws re-poisoned 0xAA before every timed call)
  hipMemsetAsync(ws + OFF_FLAGS, 0, 2048, stream);
  lrmu_all<<<256, 256, 0, stream>>>(x, K, A, Bm, out, ws);
}